// Round 6
// baseline (420.261 us; speedup 1.0000x reference)
//
#include <hip/hip_runtime.h>
#include <hip/hip_bf16.h>
#include <stdint.h>

typedef __attribute__((ext_vector_type(8))) short short8;
typedef __attribute__((ext_vector_type(8))) uint16_t ushort8;
typedef __attribute__((ext_vector_type(4))) float floatx4;

// ---------- helpers ----------

__device__ __forceinline__ uint16_t f2bf_bits(float f) {
    uint32_t u = __builtin_bit_cast(uint32_t, f);
    u += 0x7FFFu + ((u >> 16) & 1u);
    return (uint16_t)(u >> 16);
}

__device__ __forceinline__ void cvt8_one(const float* __restrict__ s, uint16_t* __restrict__ d) {
    floatx4 a = *(const floatx4*)(s);
    floatx4 b = *(const floatx4*)(s + 4);
    ushort8 o;
#pragma unroll
    for (int k = 0; k < 4; k++) { o[k] = f2bf_bits(a[k]); o[k + 4] = f2bf_bits(b[k]); }
    *(ushort8*)(d) = o;
}

// Fragment-major layout for a row-major [R][K] bf16 matrix:
// panel p = row>>4; element (row,k) at  p*16*K + ((k>>3)*16 + (row&15))*8 + (k&7).
// A wave's MFMA fragment load (rows panel, k-block) is then 64 lanes x 16B
// CONTIGUOUS (lane = (k>>3 group)*16 + row15  ->  offset lane*8 elems).
__device__ __forceinline__ size_t frag_off(int row, int kg /*k>>3*/, int K) {
    return (size_t)(row >> 4) * 16 * K + ((size_t)kg * 16 + (row & 15)) * 8;
}

// ---------- conversion kernels (write fragment-major) ----------

// X [16384][1024] fp32 -> fragment-major bf16
__global__ void cvt_x(const float* __restrict__ src, uint16_t* __restrict__ dst) {
    int g = blockIdx.x * 256 + threadIdx.x;    // over 16384*128
    int m  = g >> 7;
    int kg = g & 127;
    cvt8_one(src + (size_t)m * 1024 + kg * 8, dst + frag_off(m, kg, 1024));
}

// W0[2048][1024], W1[2048][2048], W2[51][2048]->padded 64 rows; all fragment-major
__global__ void cvt_w(const float* __restrict__ W0, const float* __restrict__ W1,
                      const float* __restrict__ W2,
                      uint16_t* __restrict__ o0, uint16_t* __restrict__ o1,
                      uint16_t* __restrict__ o2) {
    int g = blockIdx.x * 256 + threadIdx.x;
    if (g < 262144) {                       // W0: 2048 rows x 128 kg
        int r = g >> 7, kg = g & 127;
        cvt8_one(W0 + (size_t)r * 1024 + kg * 8, o0 + frag_off(r, kg, 1024));
    } else if (g < 262144 + 524288) {       // W1: 2048 rows x 256 kg
        int j = g - 262144;
        int r = j >> 8, kg = j & 255;
        cvt8_one(W1 + (size_t)r * 2048 + kg * 8, o1 + frag_off(r, kg, 2048));
    } else {                                // W2 padded: 64 rows x 256 kg
        int j = g - 786432;
        if (j < 16384) {
            int r = j >> 8, kg = j & 255;
            uint16_t* d = o2 + frag_off(r, kg, 2048);
            if (r < 51) cvt8_one(W2 + (size_t)r * 2048 + kg * 8, d);
            else { ushort8 z = {0,0,0,0,0,0,0,0}; *(ushort8*)d = z; }
        }
    }
}

// split-K reduction: out[m*51+o] = b2[o] + sum_s part[s][m][o]
__global__ void reduce_out(const float* __restrict__ part, const float* __restrict__ b2,
                           float* __restrict__ out, int M) {
    int idx = blockIdx.x * 256 + threadIdx.x;   // over M*64
    int o = idx & 63;
    if (o < 51) {
        int m = idx >> 6;
        float s = b2[o];
#pragma unroll
        for (int k = 0; k < 8; k++) s += part[(size_t)k * M * 64 + idx];
        out[m * 51 + o] = s;
    }
}

// ---------- barrier-free direct-register GEMM ----------
// C[m,n] = act( sum_k A[m,k]*W[n,k] + bias[n] );  A,W in fragment-major bf16.
// NO LDS, NO __syncthreads: each wave loads its own fragments global->VGPR
// (contiguous 1KB dwordx4 per fragment), register double-buffered so the
// compiler pipelines with fine-grained s_waitcnt vmcnt(N) — the thing the
// 2-barrier LDS structure cannot express (R4/R5 plateau at MfmaUtil~46%).
// Duplicate loads across the 2x2 waves hit same-CU L1/L2.
// Block tile (MI*32)x(NJ*32), wave tile (MI*16)x(NJ*16).
// SPLITK>1: kidx=f&7==XCD streams disjoint K-stripe; plain fp32 partials.
// Non-PARTIAL epilogue writes the NEXT layer's fragment-major bf16 (ldc=Knext).

template <int MI, int NJ, int SPLITK, bool RELU, bool PARTIAL>
__global__ __launch_bounds__(256, 3)
void gemm_direct(const uint16_t* __restrict__ A,
                 const uint16_t* __restrict__ W,
                 const float* __restrict__ bias,
                 void* __restrict__ out,
                 int M, int N, int lda, int kspan, int ldc, int nstore)
{
    constexpr int TMv = MI * 32;
    constexpr int TNv = NJ * 32;

    const int tid  = threadIdx.x;
    const int wave = tid >> 6;
    const int lane = tid & 63;

    const int f = blockIdx.x;
    int m0, n0, kbeg;
    float* opart = (float*)out;
    if constexpr (SPLITK > 1) {
        const int kidx = f & (SPLITK - 1);   // == XCD id -> disjoint K stripes
        kbeg = kidx * kspan;
        m0   = (f >> 3) * TMv;
        n0   = 0;
        opart += (size_t)kidx * M * ldc;
    } else {
        kbeg = 0;
        const int xcd = f & 7;
        const int loc = f >> 3;
        const int per = (int)gridDim.x >> 3;
        const int nt  = N / TNv;
        n0 = (loc % nt) * TNv;
        m0 = (xcd * (per / nt) + loc / nt) * TMv;
    }

    const int wr = (wave >> 1) * MI * 16;
    const int wc = (wave & 1) * NJ * 16;
    const int pa0 = (m0 + wr) >> 4;          // A panel base for this wave
    const int pb0 = (n0 + wc) >> 4;          // B (W) panel base

    floatx4 acc[MI][NJ];
    const floatx4 zero = {0.f, 0.f, 0.f, 0.f};
#pragma unroll
    for (int i = 0; i < MI; i++)
#pragma unroll
        for (int j = 0; j < NJ; j++) acc[i][j] = zero;

    // fragment pointers: contiguous 1KB per fragment, advance 512 elems per k32
    const uint16_t* ap[MI];
    const uint16_t* bp[NJ];
#pragma unroll
    for (int i = 0; i < MI; i++)
        ap[i] = A + (size_t)(pa0 + i) * 16 * lda + (size_t)kbeg * 16 + lane * 8;
#pragma unroll
    for (int j = 0; j < NJ; j++)
        bp[j] = W + (size_t)(pb0 + j) * 16 * lda + (size_t)kbeg * 16 + lane * 8;

    auto loadfr = [&](short8 (&fa)[MI], short8 (&fb)[NJ]) {
#pragma unroll
        for (int i = 0; i < MI; i++) { fa[i] = *(const short8*)ap[i]; ap[i] += 512; }
#pragma unroll
        for (int j = 0; j < NJ; j++) { fb[j] = *(const short8*)bp[j]; bp[j] += 512; }
    };
    auto domfma = [&](short8 (&fa)[MI], short8 (&fb)[NJ]) {
#pragma unroll
        for (int i = 0; i < MI; i++)
#pragma unroll
            for (int j = 0; j < NJ; j++)
                acc[i][j] = __builtin_amdgcn_mfma_f32_16x16x32_bf16(fa[i], fb[j], acc[i][j], 0, 0, 0);
    };

    short8 ca[MI], cb[NJ], na[MI], nb[NJ];
    loadfr(ca, cb);                          // k-step 0
    const int nit = kspan / 32;              // even for all layers (32/64/8)
    for (int it = 0; it < nit; it += 2) {
        loadfr(na, nb);                      // prefetch step it+1
        domfma(ca, cb);                      // compute step it
        if (it + 2 < nit) loadfr(ca, cb);    // prefetch step it+2
        domfma(na, nb);                      // compute step it+1
    }

    // epilogue: C/D layout col = lane&15, row = (lane>>4)*4 + reg
    const int cr = (lane >> 4) * 4;
    const int cc = lane & 15;
#pragma unroll
    for (int i = 0; i < MI; i++) {
        const int gmb = m0 + wr + i * 16 + cr;   // panel pa0+i, row-in-panel cr+r
#pragma unroll
        for (int j = 0; j < NJ; j++) {
            const int gn = n0 + wc + j * 16 + cc;
            if (gn < nstore) {
                float bv = 0.f;
                if constexpr (!PARTIAL) bv = bias[gn];
#pragma unroll
                for (int r = 0; r < 4; r++) {
                    float v = acc[i][j][r] + bv;
                    if (RELU) v = fmaxf(v, 0.f);
                    if constexpr (PARTIAL) {
                        opart[(size_t)(gmb + r) * ldc + gn] = v;
                    } else {
                        // write next layer's fragment-major bf16 (Knext = ldc)
                        const size_t idx = (size_t)(pa0 + i) * 16 * ldc +
                                           ((size_t)(gn >> 3) * 16 + cr + r) * 8 + (gn & 7);
                        ((uint16_t*)out)[idx] = f2bf_bits(v);
                    }
                }
            }
        }
    }
}

// ---------- launch ----------

extern "C" void kernel_launch(void* const* d_in, const int* in_sizes, int n_in,
                              void* d_out, int out_size, void* d_ws, size_t ws_size,
                              hipStream_t stream) {
    (void)in_sizes; (void)n_in; (void)out_size; (void)ws_size;
    const float* X  = (const float*)d_in[1];
    const float* W0 = (const float*)d_in[3];
    const float* b0 = (const float*)d_in[4];
    const float* W1 = (const float*)d_in[5];
    const float* b1 = (const float*)d_in[6];
    const float* W2 = (const float*)d_in[7];
    const float* b2 = (const float*)d_in[8];

    const int M = 16384;     // 16 batches * 1024 pairs

    char* w = (char*)d_ws;
    uint16_t* X0  = (uint16_t*)w; w += (size_t)M * 1024 * 2;      // 33.5 MB
    uint16_t* X1  = (uint16_t*)w; w += (size_t)M * 2048 * 2;
    uint16_t* X2  = (uint16_t*)w; w += (size_t)M * 2048 * 2;
    uint16_t* W0b = (uint16_t*)w; w += (size_t)2048 * 1024 * 2;
    uint16_t* W1b = (uint16_t*)w; w += (size_t)2048 * 2048 * 2;
    uint16_t* W2b = (uint16_t*)w; w += (size_t)64 * 2048 * 2;
    // layer-2 split-K partials [8][M][64] fp32 = 33.5 MB: alias X0 (dead after L0)
    float* part = (float*)X0;

    cvt_x<<<M * 128 / 256, 256, 0, stream>>>(X, X0);
    cvt_w<<<(262144 + 524288 + 16384) / 256, 256, 0, stream>>>(
        W0, W1, W2, W0b, W1b, W2b);

    // layer 0: [16384,1024] x [2048,1024]^T -> relu -> frag-bf16; 128x128 tiles
    gemm_direct<4, 4, 1, true, false><<<dim3((M / 128) * (2048 / 128)), 256, 0, stream>>>(
        X0, W0b, b0, X1, M, 2048, 1024, 1024, 2048, 2048);
    // layer 1: [16384,2048] x [2048,2048]^T -> relu -> frag-bf16; 128x128 tiles
    gemm_direct<4, 4, 1, true, false><<<dim3((M / 128) * (2048 / 128)), 256, 0, stream>>>(
        X1, W1b, b1, X2, M, 2048, 2048, 2048, 2048, 2048);
    // layer 2: [16384,2048] x [64(pad 51),2048]^T, split-K=8 -> fp32 partials
    gemm_direct<4, 2, 8, false, true><<<dim3((M / 128) * 8), 256, 0, stream>>>(
        X2, W2b, nullptr, part, M, 64, 2048, 256, 64, 64);
    // reduce partials + bias -> d_out [16384,51] fp32
    reduce_out<<<M * 64 / 256, 256, 0, stream>>>(part, b2, (float*)d_out, M);
}